// Round 1
// baseline (123.515 us; speedup 1.0000x reference)
//
#include <hip/hip_runtime.h>

// GraphClusterReshape: out[m, k*64 + f] = nidx[m,k] < 0 ? 0 : features[nidx[m,k], f]
// features: [100000, 64] f32, nidx: [50000, 32] i32, out: [50000, 2048] f32.
// Pure memory-bound gather: one thread per output float4 (16 B/lane).
// 16 lanes handle one neighbor row (64 floats); 4 rows per wave; stores are
// 1 KB contiguous per wave. Feature reads are 256 B contiguous per 16-lane
// group and mostly L2/L3-hit (features array = 25.6 MB < 256 MB LLC).

constexpr int K_NEIGH = 32;
constexpr int F4 = 16;        // 64 floats = 16 float4 per feature row
// output row = K_NEIGH * F4 = 512 float4  -> t>>9 = m, t&511 = q

__global__ void gcr_gather_kernel(const float4* __restrict__ feat4,
                                  const int* __restrict__ nidx,
                                  float4* __restrict__ out4,
                                  long long total4) {
    long long t = (long long)blockIdx.x * blockDim.x + threadIdx.x;
    const long long stride = (long long)gridDim.x * blockDim.x;
    for (; t < total4; t += stride) {
        const int m = (int)(t >> 9);       // / 512 float4 per output row
        const int q = (int)(t & 511);
        const int k = q >> 4;              // neighbor slot
        const int e = q & 15;              // float4 index within feature row
        const int idx = nidx[m * K_NEIGH + k];
        float4 v;
        if (idx < 0) {
            v = make_float4(0.f, 0.f, 0.f, 0.f);
        } else {
            v = feat4[(long long)idx * F4 + e];
        }
        out4[t] = v;
    }
}

extern "C" void kernel_launch(void* const* d_in, const int* in_sizes, int n_in,
                              void* d_out, int out_size, void* d_ws, size_t ws_size,
                              hipStream_t stream) {
    const float4* feat4 = (const float4*)d_in[0];   // features [100000, 64] f32
    const int*    nidx  = (const int*)d_in[1];      // nidx [50000, 32] i32
    float4*       out4  = (float4*)d_out;           // [50000, 2048] f32

    const long long total4 = (long long)out_size / 4;   // 25.6M float4

    const int block = 256;
    long long want = (total4 + block - 1) / block;
    int grid = (int)(want < 2048 ? want : 2048);    // grid-stride, ~8 blocks/CU

    gcr_gather_kernel<<<grid, block, 0, stream>>>(feat4, nidx, out4, total4);
}